// Round 10
// baseline (922.891 us; speedup 1.0000x reference)
//
#include <hip/hip_runtime.h>

#define THREADS 256
#define BSH 8        // rows per bucket = 256
#define EPB 8192     // edges per binning block (256 threads x 32)

typedef _Float16 f16;
typedef _Float16 f16x8 __attribute__((ext_vector_type(8)));
typedef _Float16 f16x4 __attribute__((ext_vector_type(4)));
typedef _Float16 f16x2 __attribute__((ext_vector_type(2)));
typedef float f32x4 __attribute__((ext_vector_type(4)));

__device__ __forceinline__ void nt_edge(const int2* ed, int idx, int& c, float& wt) {
  unsigned long long v =
      __builtin_nontemporal_load((const unsigned long long*)(ed + idx));
  c = (int)(v & 0xffffffffull);
  wt = __int_as_float((int)(v >> 32));
}

// ---------------- generic scan (1024 elems/block) ----------------

__global__ void k_scan1(const int* __restrict__ cnt, int* __restrict__ outp,
                        int* __restrict__ bsum, int n) {
  __shared__ int sh[256];
  int t = threadIdx.x;
  int base = blockIdx.x * 1024 + t * 4;
  int v[4];
#pragma unroll
  for (int j = 0; j < 4; ++j) {
    int idx = base + j;
    v[j] = (idx < n) ? cnt[idx] : 0;
  }
  int tot = v[0] + v[1] + v[2] + v[3];
  sh[t] = tot;
  __syncthreads();
  for (int off = 1; off < 256; off <<= 1) {
    int x = 0;
    if (t >= off) x = sh[t - off];
    __syncthreads();
    sh[t] += x;
    __syncthreads();
  }
  if (t == 255) bsum[blockIdx.x] = sh[255];
  int run = sh[t] - tot;
#pragma unroll
  for (int j = 0; j < 4; ++j) {
    int idx = base + j;
    if (idx < n) outp[idx] = run;
    run += v[j];
  }
}

__global__ void k_scan2(int* __restrict__ bsum, int nb) {
  __shared__ int sh[256];
  int t = threadIdx.x;
  int v = (t < nb) ? bsum[t] : 0;
  sh[t] = v;
  __syncthreads();
  for (int off = 1; off < 256; off <<= 1) {
    int x = 0;
    if (t >= off) x = sh[t - off];
    __syncthreads();
    sh[t] += x;
    __syncthreads();
  }
  if (t < nb) bsum[t] = sh[t] - v;
}

__global__ void k_scan3(int* __restrict__ outp, const int* __restrict__ bsum,
                        int n, int total) {
  int base = blockIdx.x * 1024 + threadIdx.x * 4;
  int add = bsum[blockIdx.x];
#pragma unroll
  for (int j = 0; j < 4; ++j) {
    int idx = base + j;
    if (idx < n) outp[idx] += add;
  }
  if (blockIdx.x == 0 && threadIdx.x == 0) outp[n] = total;
}

// ---------------- CSR build + layer-1 weight prep (merged front kernel) ----------------
// blocks [0, nblk): per-(bucket, block) histogram
// blocks [nblk, ...): Wt1 transpose/convert; first such block zeroes stat buffers

__global__ __launch_bounds__(256) void k_hist_convW(
    const int* __restrict__ rows, int* __restrict__ cnt2d, int e, int nblk, int nb,
    const float* __restrict__ W, f16* __restrict__ Wt, int K, int N,
    float* __restrict__ statZero) {
  int t = threadIdx.x;
  if (blockIdx.x < nblk) {
    __shared__ int hist[512];
    int blk = blockIdx.x;
    for (int i = t; i < nb; i += 256) hist[i] = 0;
    __syncthreads();
    int eb = blk * EPB;
#pragma unroll 4
    for (int it = 0; it < 32; ++it) {
      int i = eb + it * 256 + t;
      if (i < e) atomicAdd(&hist[rows[i] >> BSH], 1);
    }
    __syncthreads();
    for (int i = t; i < nb; i += 256) cnt2d[i * nblk + blk] = hist[i];
  } else {
    int cb = blockIdx.x - nblk;
    if (cb == 0) {
#pragma unroll
      for (int j = 0; j < 6; ++j) statZero[j * 256 + t] = 0.f;
    }
    int i = cb * 256 + t;
    if (i < N * K) {
      int n = i / K, k = i - n * K;
      Wt[i] = (f16)W[(size_t)k * N + n];
    }
  }
}

__global__ __launch_bounds__(256) void k_bin(
    const int* __restrict__ rows, const int* __restrict__ cols,
    const float* __restrict__ w, const int* __restrict__ off2d,
    int2* __restrict__ temp, int e, int nblk, int nb) {
  __shared__ int base[512];
  __shared__ int cursor[512];
  int blk = blockIdx.x, t = threadIdx.x;
  for (int i = t; i < nb; i += 256) {
    base[i] = off2d[i * nblk + blk];
    cursor[i] = 0;
  }
  __syncthreads();
  int eb = blk * EPB;
#pragma unroll 4
  for (int it = 0; it < 32; ++it) {
    int i = eb + it * 256 + t;
    if (i < e) {
      int r = rows[i];
      int b = r >> BSH;
      int pos = base[b] + atomicAdd(&cursor[b], 1);
      temp[pos] = make_int2(((r & 255) << 17) | cols[i], __float_as_int(w[i]));
    }
  }
}

__global__ __launch_bounds__(256) void k_scatter(
    const int2* __restrict__ temp, const int* __restrict__ off2d,
    int* __restrict__ rowptr, int2* __restrict__ ed,
    int n, int e, int nblk, int nb) {
  __shared__ int rowCnt[256];
  __shared__ int rowBase[256];
  __shared__ int rowCur[256];
  int b = blockIdx.x, t = threadIdx.x;
  int r0 = b << BSH;
  int nr = min(256, n - r0);
  int start = off2d[b * nblk];
  int end = off2d[(b + 1) * nblk];
  rowCnt[t] = 0;
  __syncthreads();
  for (int p = start + t; p < end; p += 256)
    atomicAdd(&rowCnt[temp[p].x >> 17], 1);
  __syncthreads();
  int v = rowCnt[t];
  rowBase[t] = v;
  __syncthreads();
  for (int off = 1; off < 256; off <<= 1) {
    int x = 0;
    if (t >= off) x = rowBase[t - off];
    __syncthreads();
    rowBase[t] += x;
    __syncthreads();
  }
  int excl = rowBase[t] - v;
  __syncthreads();
  rowBase[t] = excl;
  rowCur[t] = 0;
  if (t < nr) rowptr[r0 + t] = start + excl;
  if (b == nb - 1 && t == 0) rowptr[n] = e;
  __syncthreads();
  for (int p = start + t; p < end; p += 256) {
    int2 ei = temp[p];
    int ro = ei.x >> 17;
    int slot = start + rowBase[ro] + atomicAdd(&rowCur[ro], 1);
    ed[slot] = make_int2(ei.x & 0x1FFFF, ei.y);
  }
}

// ---------------- Fused BN-param + W-fold + bias-fold ----------------

__global__ __launch_bounds__(256) void k_bnfold(
    const float* __restrict__ W, const float* __restrict__ sums,
    f16* __restrict__ Wt, float* __restrict__ biasRow, int K, int N, int n) {
  __shared__ float sc[256], sf[256];
  int t = threadIdx.x;
  if (t < K) {
    float inv = 1.0f / (float)n;
    float mean = sums[t] * inv;
    float var = sums[256 + t] * inv - mean * mean;
    float rstd = rsqrtf(var + 1e-5f);
    sc[t] = rstd;
    sf[t] = -mean * rstd;
  }
  __syncthreads();
  int i = blockIdx.x * 256 + t;
  if (i < N * K) {
    int nn = i / K, k = i - nn * K;
    Wt[i] = (f16)(sc[k] * W[(size_t)k * N + nn]);
  }
  if (blockIdx.x < (K >> 4) && t < N) {
    int k0 = blockIdx.x * 16;
    float s = 0.f;
#pragma unroll
    for (int j = 0; j < 16; ++j) s += sf[k0 + j] * W[(size_t)(k0 + j) * N + t];
    atomicAdd(&biasRow[t], s);
  }
}

// ---------------- MFMA GEMM: Csup[M][BN] = A[M][K] @ Wt^T + biasRow, f16 out ----

template <int BN, bool AF16>
__global__ __launch_bounds__(256) void k_gemm_mfma(
    const void* __restrict__ Ap, const f16* __restrict__ Wt,
    const float* __restrict__ biasRow, f16* __restrict__ Csup, int M, int K) {
  constexpr int BM = 128;
  constexpr int BK = 32;
  constexpr int LDT = BK + 8;
  __shared__ __align__(16) f16 As[BM][LDT];
  __shared__ __align__(16) f16 Bs[BN][LDT];

  const int tid = threadIdx.x;
  const int wave = tid >> 6;
  const int lane = tid & 63;
  const int m0 = blockIdx.x * BM;
  constexpr int WM = (BN == 256) ? 8 : 2;
  constexpr int WN = 4;
  const int wrow = (BN == 256) ? 0 : wave * 32;
  const int wcol = (BN == 256) ? wave * 64 : 0;
  const int l15 = lane & 15;
  const int lq = lane >> 4;

  const int arow = tid >> 1;
  const int akofs = (tid & 1) * 16;
  const int srow = tid >> 2;
  const int skofs = (tid & 3) * 8;
  constexpr int BROWS = BN / 64;

  f32x4 acc[WM][WN] = {};

  for (int k0 = 0; k0 < K; k0 += BK) {
    f16x8 a16[2];
    int gr = m0 + arow;
    if constexpr (AF16) {
      if (gr < M) {
        const f16* ap = (const f16*)Ap + (size_t)gr * K + k0 + akofs;
        a16[0] = *(const f16x8*)ap;
        a16[1] = *(const f16x8*)(ap + 8);
      } else {
#pragma unroll
        for (int j = 0; j < 8; ++j) { a16[0][j] = (f16)0.f; a16[1][j] = (f16)0.f; }
      }
    } else {
      float va[16];
      if (gr < M) {
        const float* ap = (const float*)Ap + (size_t)gr * K + k0 + akofs;
#pragma unroll
        for (int q = 0; q < 4; ++q) *(float4*)&va[q * 4] = *(const float4*)(ap + q * 4);
      } else {
#pragma unroll
        for (int j = 0; j < 16; ++j) va[j] = 0.f;
      }
#pragma unroll
      for (int j = 0; j < 8; ++j) { a16[0][j] = (f16)va[j]; a16[1][j] = (f16)va[8 + j]; }
    }

    f16x8 vb[BROWS];
#pragma unroll
    for (int j = 0; j < BROWS; ++j)
      vb[j] = *(const f16x8*)(Wt + (size_t)(srow + j * 64) * K + k0 + skofs);

    __syncthreads();
    *(f16x8*)&As[arow][akofs] = a16[0];
    *(f16x8*)&As[arow][akofs + 8] = a16[1];
#pragma unroll
    for (int j = 0; j < BROWS; ++j) *(f16x8*)&Bs[srow + j * 64][skofs] = vb[j];
    __syncthreads();

    f16x8 af[WM], bf[WN];
#pragma unroll
    for (int m = 0; m < WM; ++m)
      af[m] = *(const f16x8*)&As[wrow + m * 16 + l15][lq * 8];
#pragma unroll
    for (int n = 0; n < WN; ++n)
      bf[n] = *(const f16x8*)&Bs[wcol + n * 16 + l15][lq * 8];
#pragma unroll
    for (int m = 0; m < WM; ++m)
#pragma unroll
      for (int n = 0; n < WN; ++n)
        acc[m][n] = __builtin_amdgcn_mfma_f32_16x16x32_f16(af[m], bf[n], acc[m][n], 0, 0, 0);
  }

  float bb[WN];
#pragma unroll
  for (int n = 0; n < WN; ++n)
    bb[n] = biasRow ? biasRow[wcol + n * 16 + l15] : 0.f;

#pragma unroll
  for (int m = 0; m < WM; ++m) {
#pragma unroll
    for (int r = 0; r < 4; ++r) {
      int row = m0 + wrow + m * 16 + lq * 4 + r;
      if (row < M) {
        f16* cp = Csup + (size_t)row * BN + wcol + l15;
#pragma unroll
        for (int n = 0; n < WN; ++n) cp[n * 16] = (f16)(acc[m][n][r] + bb[n]);
      }
    }
  }
}

// ---------------- Aggregation D=256: one WAVE per row, 16-deep, nt edge loads ----

__global__ __launch_bounds__(256) void k_agg256(
    const f16* __restrict__ sup, const int* __restrict__ rowptr,
    const int2* __restrict__ ed, const float* __restrict__ bias,
    f16* __restrict__ out, int n) {
  int wid = (blockIdx.x * THREADS + threadIdx.x) >> 6;
  int lane = threadIdx.x & 63;
  if (wid >= n) return;
  int p0 = rowptr[wid], p1 = rowptr[wid + 1];

  const f16x4* supv = (const f16x4*)sup;
  float acc[4][4] = {};
  int p = p0;
  for (; p + 16 <= p1; p += 16) {
    int c[16];
    float wt[16];
#pragma unroll
    for (int j = 0; j < 16; ++j) nt_edge(ed, p + j, c[j], wt[j]);
    f16x4 v[16];
#pragma unroll
    for (int j = 0; j < 16; ++j) v[j] = supv[(size_t)c[j] * 64 + lane];
#pragma unroll
    for (int j = 0; j < 16; ++j) {
      acc[j & 3][0] += wt[j] * (float)v[j][0];
      acc[j & 3][1] += wt[j] * (float)v[j][1];
      acc[j & 3][2] += wt[j] * (float)v[j][2];
      acc[j & 3][3] += wt[j] * (float)v[j][3];
    }
  }
  for (; p + 4 <= p1; p += 4) {
    int c[4];
    float wt[4];
#pragma unroll
    for (int j = 0; j < 4; ++j) nt_edge(ed, p + j, c[j], wt[j]);
    f16x4 v[4];
#pragma unroll
    for (int j = 0; j < 4; ++j) v[j] = supv[(size_t)c[j] * 64 + lane];
#pragma unroll
    for (int j = 0; j < 4; ++j) {
      acc[j][0] += wt[j] * (float)v[j][0];
      acc[j][1] += wt[j] * (float)v[j][1];
      acc[j][2] += wt[j] * (float)v[j][2];
      acc[j][3] += wt[j] * (float)v[j][3];
    }
  }
  for (; p < p1; ++p) {
    int c;
    float wt;
    nt_edge(ed, p, c, wt);
    f16x4 v = supv[(size_t)c * 64 + lane];
    acc[0][0] += wt * (float)v[0];
    acc[0][1] += wt * (float)v[1];
    acc[0][2] += wt * (float)v[2];
    acc[0][3] += wt * (float)v[3];
  }
  float4 b = *(const float4*)(bias + lane * 4);
  f16x4 r;
  r[0] = (f16)fmaxf(acc[0][0] + acc[1][0] + acc[2][0] + acc[3][0] + b.x, 0.f);
  r[1] = (f16)fmaxf(acc[0][1] + acc[1][1] + acc[2][1] + acc[3][1] + b.y, 0.f);
  r[2] = (f16)fmaxf(acc[0][2] + acc[1][2] + acc[2][2] + acc[3][2] + b.z, 0.f);
  r[3] = (f16)fmaxf(acc[0][3] + acc[1][3] + acc[2][3] + acc[3][3] + b.w, 0.f);
  *(f16x4*)(out + (size_t)wid * 256 + lane * 4) = r;
}

// ---------------- Aggregation D=64: one WAVE per row, quarter-wave edge slots ----
// quarter q (16 lanes) handles edge p+4j+q; each lane loads f16x4 (4 cols, 8B).
// 8-step main loop = 32 edges in flight; shfl_xor(16|32) merges quarters.

__global__ __launch_bounds__(256) void k_agg64(
    const f16* __restrict__ sup, const int* __restrict__ rowptr,
    const int2* __restrict__ ed, const float* __restrict__ bias,
    float* __restrict__ out, int n) {
  int wid = (blockIdx.x * THREADS + threadIdx.x) >> 6;
  int lane = threadIdx.x & 63;
  if (wid >= n) return;
  int p0 = rowptr[wid], p1 = rowptr[wid + 1];
  int q = lane >> 4;    // edge slot 0..3
  int hl = lane & 15;   // col group of 4

  const f16x4* supv = (const f16x4*)sup;  // 16 groups per 64-col row
  float acc[2][4] = {};
  int p = p0;
  for (; p + 32 <= p1; p += 32) {
    int c[8];
    float wt[8];
#pragma unroll
    for (int j = 0; j < 8; ++j) nt_edge(ed, p + 4 * j + q, c[j], wt[j]);
    f16x4 v[8];
#pragma unroll
    for (int j = 0; j < 8; ++j) v[j] = supv[(size_t)c[j] * 16 + hl];
#pragma unroll
    for (int j = 0; j < 8; ++j) {
      acc[j & 1][0] += wt[j] * (float)v[j][0];
      acc[j & 1][1] += wt[j] * (float)v[j][1];
      acc[j & 1][2] += wt[j] * (float)v[j][2];
      acc[j & 1][3] += wt[j] * (float)v[j][3];
    }
  }
  for (; p + 4 <= p1; p += 4) {
    int c;
    float wt;
    nt_edge(ed, p + q, c, wt);
    f16x4 v = supv[(size_t)c * 16 + hl];
    acc[0][0] += wt * (float)v[0];
    acc[0][1] += wt * (float)v[1];
    acc[0][2] += wt * (float)v[2];
    acc[0][3] += wt * (float)v[3];
  }
  if (p < p1) {  // tail < 4 edges, masked slot
    int idx = p + q;
    int c = 0;
    float wt = 0.f;
    if (idx < p1) nt_edge(ed, idx, c, wt);
    f16x4 v = supv[(size_t)c * 16 + hl];
    acc[0][0] += wt * (float)v[0];
    acc[0][1] += wt * (float)v[1];
    acc[0][2] += wt * (float)v[2];
    acc[0][3] += wt * (float)v[3];
  }
  float t0 = acc[0][0] + acc[1][0];
  float t1 = acc[0][1] + acc[1][1];
  float t2 = acc[0][2] + acc[1][2];
  float t3 = acc[0][3] + acc[1][3];
  t0 += __shfl_xor(t0, 16); t0 += __shfl_xor(t0, 32);
  t1 += __shfl_xor(t1, 16); t1 += __shfl_xor(t1, 32);
  t2 += __shfl_xor(t2, 16); t2 += __shfl_xor(t2, 32);
  t3 += __shfl_xor(t3, 16); t3 += __shfl_xor(t3, 32);
  if (q == 0) {
    float4 b = *(const float4*)(bias + hl * 4);
    float4 res;
    res.x = fmaxf(t0 + b.x, 0.f);
    res.y = fmaxf(t1 + b.y, 0.f);
    res.z = fmaxf(t2 + b.z, 0.f);
    res.w = fmaxf(t3 + b.w, 0.f);
    *(float4*)(out + (size_t)wid * 64 + hl * 4) = res;
  }
}

// ---------------- BN stats ----------------

__global__ __launch_bounds__(256) void k_colstats(const f16* __restrict__ y,
                                                  float* __restrict__ sums, int n) {
  __shared__ float sh[8][256];
  int t = threadIdx.x;
  int cg = (t & 31) * 8;
  int rs = t >> 5;
  float s[8] = {}, s2[8] = {};
  for (int r = blockIdx.x * 8 + rs; r < n; r += gridDim.x * 8) {
    f16x8 v = *(const f16x8*)(y + (size_t)r * 256 + cg);
#pragma unroll
    for (int j = 0; j < 8; ++j) {
      float f = (float)v[j];
      s[j] += f;
      s2[j] += f * f;
    }
  }
#pragma unroll
  for (int j = 0; j < 8; ++j) sh[rs][cg + j] = s[j];
  __syncthreads();
  float tot = 0.f;
#pragma unroll
  for (int k = 0; k < 8; ++k) tot += sh[k][t];
  atomicAdd(&sums[t], tot);
  __syncthreads();
#pragma unroll
  for (int j = 0; j < 8; ++j) sh[rs][cg + j] = s2[j];
  __syncthreads();
  tot = 0.f;
#pragma unroll
  for (int k = 0; k < 8; ++k) tot += sh[k][t];
  atomicAdd(&sums[256 + t], tot);
}

// ---------------- launch ----------------

extern "C" void kernel_launch(void* const* d_in, const int* in_sizes, int n_in,
                              void* d_out, int out_size, void* d_ws, size_t ws_size,
                              hipStream_t stream) {
  const float* x = (const float*)d_in[0];
  const int* ei = (const int*)d_in[1];
  const float* ew = (const float*)d_in[2];
  const float* W1 = (const float*)d_in[3];
  const float* b1 = (const float*)d_in[4];
  const float* W2 = (const float*)d_in[5];
  const float* b2 = (const float*)d_in[6];
  const float* W3 = (const float*)d_in[7];
  const float* b3 = (const float*)d_in[8];
  float* out = (float*)d_out;

  const int N = in_sizes[0] / 512;  // 100000
  const int E = in_sizes[2];        // 3200000

  const int NB = (N + 255) >> BSH;
  const int NBLK = (E + EPB - 1) / EPB;
  const int scanN = NB * NBLK;

  char* p = (char*)d_ws;
  auto alloc = [&](size_t bytes) {
    void* r = (void*)p;
    p += (bytes + 255) & ~(size_t)255;
    return r;
  };
  int* rowptr = (int*)alloc((size_t)(N + 1) * 4);
  int* cnt2d = (int*)alloc((size_t)scanN * 4);
  int* off2d = (int*)alloc((size_t)(scanN + 1) * 4);
  int* bsum = (int*)alloc(4096);
  float* statZ = (float*)alloc(1536 * 4);
  float* sumsA = statZ;
  float* sumsB = statZ + 512;
  float* biasRowA = statZ + 1024;
  float* biasRowB = statZ + 1280;
  f16* Wt1 = (f16*)alloc((size_t)512 * 256 * 2);
  f16* Wt2 = (f16*)alloc((size_t)256 * 256 * 2);
  f16* Wt3 = (f16*)alloc((size_t)256 * 64 * 2);
  int2* temp = (int2*)alloc((size_t)E * 8);
  int2* ed = (int2*)alloc((size_t)E * 8);
  f16* sup = (f16*)alloc((size_t)N * 256 * 2);
  f16* act = (f16*)alloc((size_t)N * 256 * 2);

  const int* rows = ei;
  const int* colsIn = ei + E;

  // --- CSR build front: hist + Wt1 conversion in ONE dispatch ---
  const int convBlocks = (512 * 256 + 255) / 256;
  k_hist_convW<<<NBLK + convBlocks, 256, 0, stream>>>(
      rows, cnt2d, E, NBLK, NB, W1, Wt1, 512, 256, statZ);
  int nbs = (scanN + 1023) / 1024;
  k_scan1<<<nbs, 256, 0, stream>>>(cnt2d, off2d, bsum, scanN);
  k_scan2<<<1, 256, 0, stream>>>(bsum, nbs);
  k_scan3<<<nbs, 256, 0, stream>>>(off2d, bsum, scanN, E);
  k_bin<<<NBLK, 256, 0, stream>>>(rows, colsIn, ew, off2d, temp, E, NBLK, NB);
  k_scatter<<<NB, 256, 0, stream>>>(temp, off2d, rowptr, ed, N, E, NBLK, NB);

  const int gemmBlocks = (N + 127) / 128;
  const int aggBlocks = (N * 64 + THREADS - 1) / THREADS;

  // --- Layer 1 ---
  k_gemm_mfma<256, false><<<gemmBlocks, 256, 0, stream>>>(x, Wt1, nullptr, sup, N, 512);
  k_agg256<<<aggBlocks, 256, 0, stream>>>(sup, rowptr, ed, b1, act, N);

  // --- BN1 + fold into W2 ---
  k_colstats<<<240, 256, 0, stream>>>(act, sumsA, N);
  k_bnfold<<<(256 * 256 + 255) / 256, 256, 0, stream>>>(W2, sumsA, Wt2, biasRowA, 256, 256, N);

  // --- Layer 2 ---
  k_gemm_mfma<256, true><<<gemmBlocks, 256, 0, stream>>>(act, Wt2, biasRowA, sup, N, 256);
  k_agg256<<<aggBlocks, 256, 0, stream>>>(sup, rowptr, ed, b2, act, N);

  // --- BN2 + fold into W3 ---
  k_colstats<<<240, 256, 0, stream>>>(act, sumsB, N);
  k_bnfold<<<(256 * 64 + 255) / 256, 256, 0, stream>>>(W3, sumsB, Wt3, biasRowB, 256, 64, N);

  // --- Layer 3 ---
  k_gemm_mfma<64, true><<<gemmBlocks, 256, 0, stream>>>(act, Wt3, biasRowB, sup, N, 256);
  k_agg64<<<aggBlocks, 256, 0, stream>>>(sup, rowptr, ed, b3, out, N);
}

// Round 11
// 884.619 us; speedup vs baseline: 1.0433x; 1.0433x over previous
//
#include <hip/hip_runtime.h>

#define THREADS 256
#define BSH 8        // rows per bucket = 256
#define EPB 8192     // edges per binning block (256 threads x 32)

typedef _Float16 f16;
typedef _Float16 f16x8 __attribute__((ext_vector_type(8)));
typedef _Float16 f16x4 __attribute__((ext_vector_type(4)));
typedef float f32x4 __attribute__((ext_vector_type(4)));

// ---------------- generic scan (1024 elems/block) ----------------

__global__ void k_scan1(const int* __restrict__ cnt, int* __restrict__ outp,
                        int* __restrict__ bsum, int n) {
  __shared__ int sh[256];
  int t = threadIdx.x;
  int base = blockIdx.x * 1024 + t * 4;
  int v[4];
#pragma unroll
  for (int j = 0; j < 4; ++j) {
    int idx = base + j;
    v[j] = (idx < n) ? cnt[idx] : 0;
  }
  int tot = v[0] + v[1] + v[2] + v[3];
  sh[t] = tot;
  __syncthreads();
  for (int off = 1; off < 256; off <<= 1) {
    int x = 0;
    if (t >= off) x = sh[t - off];
    __syncthreads();
    sh[t] += x;
    __syncthreads();
  }
  if (t == 255) bsum[blockIdx.x] = sh[255];
  int run = sh[t] - tot;
#pragma unroll
  for (int j = 0; j < 4; ++j) {
    int idx = base + j;
    if (idx < n) outp[idx] = run;
    run += v[j];
  }
}

__global__ void k_scan2(int* __restrict__ bsum, int nb) {
  __shared__ int sh[256];
  int t = threadIdx.x;
  int v = (t < nb) ? bsum[t] : 0;
  sh[t] = v;
  __syncthreads();
  for (int off = 1; off < 256; off <<= 1) {
    int x = 0;
    if (t >= off) x = sh[t - off];
    __syncthreads();
    sh[t] += x;
    __syncthreads();
  }
  if (t < nb) bsum[t] = sh[t] - v;
}

__global__ void k_scan3(int* __restrict__ outp, const int* __restrict__ bsum,
                        int n, int total) {
  int base = blockIdx.x * 1024 + threadIdx.x * 4;
  int add = bsum[blockIdx.x];
#pragma unroll
  for (int j = 0; j < 4; ++j) {
    int idx = base + j;
    if (idx < n) outp[idx] += add;
  }
  if (blockIdx.x == 0 && threadIdx.x == 0) outp[n] = total;
}

// ---------------- CSR build + layer-1 weight prep (merged front kernel) ----------------

__global__ __launch_bounds__(256) void k_hist_convW(
    const int* __restrict__ rows, int* __restrict__ cnt2d, int e, int nblk, int nb,
    const float* __restrict__ W, f16* __restrict__ Wt, int K, int N,
    float* __restrict__ statZero) {
  int t = threadIdx.x;
  if (blockIdx.x < nblk) {
    __shared__ int hist[512];
    int blk = blockIdx.x;
    for (int i = t; i < nb; i += 256) hist[i] = 0;
    __syncthreads();
    int eb = blk * EPB;
#pragma unroll 4
    for (int it = 0; it < 32; ++it) {
      int i = eb + it * 256 + t;
      if (i < e) atomicAdd(&hist[rows[i] >> BSH], 1);
    }
    __syncthreads();
    for (int i = t; i < nb; i += 256) cnt2d[i * nblk + blk] = hist[i];
  } else {
    int cb = blockIdx.x - nblk;
    if (cb == 0) {
#pragma unroll
      for (int j = 0; j < 6; ++j) statZero[j * 256 + t] = 0.f;
    }
    int i = cb * 256 + t;
    if (i < N * K) {
      int n = i / K, k = i - n * K;
      Wt[i] = (f16)W[(size_t)k * N + n];
    }
  }
}

__global__ __launch_bounds__(256) void k_bin(
    const int* __restrict__ rows, const int* __restrict__ cols,
    const float* __restrict__ w, const int* __restrict__ off2d,
    int2* __restrict__ temp, int e, int nblk, int nb) {
  __shared__ int base[512];
  __shared__ int cursor[512];
  int blk = blockIdx.x, t = threadIdx.x;
  for (int i = t; i < nb; i += 256) {
    base[i] = off2d[i * nblk + blk];
    cursor[i] = 0;
  }
  __syncthreads();
  int eb = blk * EPB;
#pragma unroll 4
  for (int it = 0; it < 32; ++it) {
    int i = eb + it * 256 + t;
    if (i < e) {
      int r = rows[i];
      int b = r >> BSH;
      int pos = base[b] + atomicAdd(&cursor[b], 1);
      temp[pos] = make_int2(((r & 255) << 17) | cols[i], __float_as_int(w[i]));
    }
  }
}

__global__ __launch_bounds__(256) void k_scatter(
    const int2* __restrict__ temp, const int* __restrict__ off2d,
    int* __restrict__ rowptr, int2* __restrict__ ed,
    int n, int e, int nblk, int nb) {
  __shared__ int rowCnt[256];
  __shared__ int rowBase[256];
  __shared__ int rowCur[256];
  int b = blockIdx.x, t = threadIdx.x;
  int r0 = b << BSH;
  int nr = min(256, n - r0);
  int start = off2d[b * nblk];
  int end = off2d[(b + 1) * nblk];
  rowCnt[t] = 0;
  __syncthreads();
  for (int p = start + t; p < end; p += 256)
    atomicAdd(&rowCnt[temp[p].x >> 17], 1);
  __syncthreads();
  int v = rowCnt[t];
  rowBase[t] = v;
  __syncthreads();
  for (int off = 1; off < 256; off <<= 1) {
    int x = 0;
    if (t >= off) x = rowBase[t - off];
    __syncthreads();
    rowBase[t] += x;
    __syncthreads();
  }
  int excl = rowBase[t] - v;
  __syncthreads();
  rowBase[t] = excl;
  rowCur[t] = 0;
  if (t < nr) rowptr[r0 + t] = start + excl;
  if (b == nb - 1 && t == 0) rowptr[n] = e;
  __syncthreads();
  for (int p = start + t; p < end; p += 256) {
    int2 ei = temp[p];
    int ro = ei.x >> 17;
    int slot = start + rowBase[ro] + atomicAdd(&rowCur[ro], 1);
    ed[slot] = make_int2(ei.x & 0x1FFFF, ei.y);
  }
}

// ---------------- Fused BN-param + W-fold + bias-fold ----------------

__global__ __launch_bounds__(256) void k_bnfold(
    const float* __restrict__ W, const float* __restrict__ sums,
    f16* __restrict__ Wt, float* __restrict__ biasRow, int K, int N, int n) {
  __shared__ float sc[256], sf[256];
  int t = threadIdx.x;
  if (t < K) {
    float inv = 1.0f / (float)n;
    float mean = sums[t] * inv;
    float var = sums[256 + t] * inv - mean * mean;
    float rstd = rsqrtf(var + 1e-5f);
    sc[t] = rstd;
    sf[t] = -mean * rstd;
  }
  __syncthreads();
  int i = blockIdx.x * 256 + t;
  if (i < N * K) {
    int nn = i / K, k = i - nn * K;
    Wt[i] = (f16)(sc[k] * W[(size_t)k * N + nn]);
  }
  if (blockIdx.x < (K >> 4) && t < N) {
    int k0 = blockIdx.x * 16;
    float s = 0.f;
#pragma unroll
    for (int j = 0; j < 16; ++j) s += sf[k0 + j] * W[(size_t)(k0 + j) * N + t];
    atomicAdd(&biasRow[t], s);
  }
}

// ---------------- MFMA GEMM: Csup[M][BN] = A[M][K] @ Wt^T + biasRow, f16 out ----

template <int BN, bool AF16>
__global__ __launch_bounds__(256) void k_gemm_mfma(
    const void* __restrict__ Ap, const f16* __restrict__ Wt,
    const float* __restrict__ biasRow, f16* __restrict__ Csup, int M, int K) {
  constexpr int BM = 128;
  constexpr int BK = 32;
  constexpr int LDT = BK + 8;
  __shared__ __align__(16) f16 As[BM][LDT];
  __shared__ __align__(16) f16 Bs[BN][LDT];

  const int tid = threadIdx.x;
  const int wave = tid >> 6;
  const int lane = tid & 63;
  const int m0 = blockIdx.x * BM;
  constexpr int WM = (BN == 256) ? 8 : 2;
  constexpr int WN = 4;
  const int wrow = (BN == 256) ? 0 : wave * 32;
  const int wcol = (BN == 256) ? wave * 64 : 0;
  const int l15 = lane & 15;
  const int lq = lane >> 4;

  const int arow = tid >> 1;
  const int akofs = (tid & 1) * 16;
  const int srow = tid >> 2;
  const int skofs = (tid & 3) * 8;
  constexpr int BROWS = BN / 64;

  f32x4 acc[WM][WN] = {};

  for (int k0 = 0; k0 < K; k0 += BK) {
    f16x8 a16[2];
    int gr = m0 + arow;
    if constexpr (AF16) {
      if (gr < M) {
        const f16* ap = (const f16*)Ap + (size_t)gr * K + k0 + akofs;
        a16[0] = *(const f16x8*)ap;
        a16[1] = *(const f16x8*)(ap + 8);
      } else {
#pragma unroll
        for (int j = 0; j < 8; ++j) { a16[0][j] = (f16)0.f; a16[1][j] = (f16)0.f; }
      }
    } else {
      float va[16];
      if (gr < M) {
        const float* ap = (const float*)Ap + (size_t)gr * K + k0 + akofs;
#pragma unroll
        for (int q = 0; q < 4; ++q) *(float4*)&va[q * 4] = *(const float4*)(ap + q * 4);
      } else {
#pragma unroll
        for (int j = 0; j < 16; ++j) va[j] = 0.f;
      }
#pragma unroll
      for (int j = 0; j < 8; ++j) { a16[0][j] = (f16)va[j]; a16[1][j] = (f16)va[8 + j]; }
    }

    f16x8 vb[BROWS];
#pragma unroll
    for (int j = 0; j < BROWS; ++j)
      vb[j] = *(const f16x8*)(Wt + (size_t)(srow + j * 64) * K + k0 + skofs);

    __syncthreads();
    *(f16x8*)&As[arow][akofs] = a16[0];
    *(f16x8*)&As[arow][akofs + 8] = a16[1];
#pragma unroll
    for (int j = 0; j < BROWS; ++j) *(f16x8*)&Bs[srow + j * 64][skofs] = vb[j];
    __syncthreads();

    f16x8 af[WM], bf[WN];
#pragma unroll
    for (int m = 0; m < WM; ++m)
      af[m] = *(const f16x8*)&As[wrow + m * 16 + l15][lq * 8];
#pragma unroll
    for (int n = 0; n < WN; ++n)
      bf[n] = *(const f16x8*)&Bs[wcol + n * 16 + l15][lq * 8];
#pragma unroll
    for (int m = 0; m < WM; ++m)
#pragma unroll
      for (int n = 0; n < WN; ++n)
        acc[m][n] = __builtin_amdgcn_mfma_f32_16x16x32_f16(af[m], bf[n], acc[m][n], 0, 0, 0);
  }

  float bb[WN];
#pragma unroll
  for (int n = 0; n < WN; ++n)
    bb[n] = biasRow ? biasRow[wcol + n * 16 + l15] : 0.f;

#pragma unroll
  for (int m = 0; m < WM; ++m) {
#pragma unroll
    for (int r = 0; r < 4; ++r) {
      int row = m0 + wrow + m * 16 + lq * 4 + r;
      if (row < M) {
        f16* cp = Csup + (size_t)row * BN + wcol + l15;
#pragma unroll
        for (int n = 0; n < WN; ++n) cp[n * 16] = (f16)(acc[m][n][r] + bb[n]);
      }
    }
  }
}

// ---------------- Aggregation D=256: one WAVE per row, 16-deep gather pipeline ----

__global__ __launch_bounds__(256) void k_agg256(
    const f16* __restrict__ sup, const int* __restrict__ rowptr,
    const int2* __restrict__ ed, const float* __restrict__ bias,
    f16* __restrict__ out, int n) {
  int wid = (blockIdx.x * THREADS + threadIdx.x) >> 6;
  int lane = threadIdx.x & 63;
  if (wid >= n) return;
  int p0 = rowptr[wid], p1 = rowptr[wid + 1];

  const f16x4* supv = (const f16x4*)sup;
  float acc[4][4] = {};
  int p = p0;
  for (; p + 16 <= p1; p += 16) {
    int2 e[16];
#pragma unroll
    for (int j = 0; j < 16; ++j) e[j] = ed[p + j];
    f16x4 v[16];
#pragma unroll
    for (int j = 0; j < 16; ++j) v[j] = supv[(size_t)e[j].x * 64 + lane];
#pragma unroll
    for (int j = 0; j < 16; ++j) {
      float wt = __int_as_float(e[j].y);
      acc[j & 3][0] += wt * (float)v[j][0];
      acc[j & 3][1] += wt * (float)v[j][1];
      acc[j & 3][2] += wt * (float)v[j][2];
      acc[j & 3][3] += wt * (float)v[j][3];
    }
  }
  for (; p + 4 <= p1; p += 4) {
    int2 e[4];
#pragma unroll
    for (int j = 0; j < 4; ++j) e[j] = ed[p + j];
    f16x4 v[4];
#pragma unroll
    for (int j = 0; j < 4; ++j) v[j] = supv[(size_t)e[j].x * 64 + lane];
#pragma unroll
    for (int j = 0; j < 4; ++j) {
      float wt = __int_as_float(e[j].y);
      acc[j][0] += wt * (float)v[j][0];
      acc[j][1] += wt * (float)v[j][1];
      acc[j][2] += wt * (float)v[j][2];
      acc[j][3] += wt * (float)v[j][3];
    }
  }
  for (; p < p1; ++p) {
    int2 e0 = ed[p];
    float wt = __int_as_float(e0.y);
    f16x4 v = supv[(size_t)e0.x * 64 + lane];
    acc[0][0] += wt * (float)v[0];
    acc[0][1] += wt * (float)v[1];
    acc[0][2] += wt * (float)v[2];
    acc[0][3] += wt * (float)v[3];
  }
  float4 b = *(const float4*)(bias + lane * 4);
  f16x4 r;
  r[0] = (f16)fmaxf(acc[0][0] + acc[1][0] + acc[2][0] + acc[3][0] + b.x, 0.f);
  r[1] = (f16)fmaxf(acc[0][1] + acc[1][1] + acc[2][1] + acc[3][1] + b.y, 0.f);
  r[2] = (f16)fmaxf(acc[0][2] + acc[1][2] + acc[2][2] + acc[3][2] + b.z, 0.f);
  r[3] = (f16)fmaxf(acc[0][3] + acc[1][3] + acc[2][3] + acc[3][3] + b.w, 0.f);
  *(f16x4*)(out + (size_t)wid * 256 + lane * 4) = r;
}

// ---------------- Aggregation D=64: one WAVE per row, quarter-wave edge slots ----
// quarter q (16 lanes) handles edge p+4j+q; each lane loads f16x4 (4 cols, 8B).
// 8-step main loop = 32 edges in flight; shfl_xor(16|32) merges quarters.

__global__ __launch_bounds__(256) void k_agg64(
    const f16* __restrict__ sup, const int* __restrict__ rowptr,
    const int2* __restrict__ ed, const float* __restrict__ bias,
    float* __restrict__ out, int n) {
  int wid = (blockIdx.x * THREADS + threadIdx.x) >> 6;
  int lane = threadIdx.x & 63;
  if (wid >= n) return;
  int p0 = rowptr[wid], p1 = rowptr[wid + 1];
  int q = lane >> 4;    // edge slot 0..3
  int hl = lane & 15;   // col group of 4

  const f16x4* supv = (const f16x4*)sup;  // 16 groups per 64-col row
  float acc[2][4] = {};
  int p = p0;
  for (; p + 32 <= p1; p += 32) {
    int2 e[8];
#pragma unroll
    for (int j = 0; j < 8; ++j) e[j] = ed[p + 4 * j + q];
    f16x4 v[8];
#pragma unroll
    for (int j = 0; j < 8; ++j) v[j] = supv[(size_t)e[j].x * 16 + hl];
#pragma unroll
    for (int j = 0; j < 8; ++j) {
      float wt = __int_as_float(e[j].y);
      acc[j & 1][0] += wt * (float)v[j][0];
      acc[j & 1][1] += wt * (float)v[j][1];
      acc[j & 1][2] += wt * (float)v[j][2];
      acc[j & 1][3] += wt * (float)v[j][3];
    }
  }
  for (; p + 4 <= p1; p += 4) {
    int2 e0 = ed[p + q];
    float wt = __int_as_float(e0.y);
    f16x4 v = supv[(size_t)e0.x * 16 + hl];
    acc[0][0] += wt * (float)v[0];
    acc[0][1] += wt * (float)v[1];
    acc[0][2] += wt * (float)v[2];
    acc[0][3] += wt * (float)v[3];
  }
  if (p < p1) {  // tail < 4 edges, masked slot
    int idx = p + q;
    int c = 0;
    float wt = 0.f;
    if (idx < p1) {
      int2 e0 = ed[idx];
      c = e0.x;
      wt = __int_as_float(e0.y);
    }
    f16x4 v = supv[(size_t)c * 16 + hl];
    acc[0][0] += wt * (float)v[0];
    acc[0][1] += wt * (float)v[1];
    acc[0][2] += wt * (float)v[2];
    acc[0][3] += wt * (float)v[3];
  }
  float t0 = acc[0][0] + acc[1][0];
  float t1 = acc[0][1] + acc[1][1];
  float t2 = acc[0][2] + acc[1][2];
  float t3 = acc[0][3] + acc[1][3];
  t0 += __shfl_xor(t0, 16); t0 += __shfl_xor(t0, 32);
  t1 += __shfl_xor(t1, 16); t1 += __shfl_xor(t1, 32);
  t2 += __shfl_xor(t2, 16); t2 += __shfl_xor(t2, 32);
  t3 += __shfl_xor(t3, 16); t3 += __shfl_xor(t3, 32);
  if (q == 0) {
    float4 b = *(const float4*)(bias + hl * 4);
    float4 res;
    res.x = fmaxf(t0 + b.x, 0.f);
    res.y = fmaxf(t1 + b.y, 0.f);
    res.z = fmaxf(t2 + b.z, 0.f);
    res.w = fmaxf(t3 + b.w, 0.f);
    *(float4*)(out + (size_t)wid * 64 + hl * 4) = res;
  }
}

// ---------------- BN stats ----------------

__global__ __launch_bounds__(256) void k_colstats(const f16* __restrict__ y,
                                                  float* __restrict__ sums, int n) {
  __shared__ float sh[8][256];
  int t = threadIdx.x;
  int cg = (t & 31) * 8;
  int rs = t >> 5;
  float s[8] = {}, s2[8] = {};
  for (int r = blockIdx.x * 8 + rs; r < n; r += gridDim.x * 8) {
    f16x8 v = *(const f16x8*)(y + (size_t)r * 256 + cg);
#pragma unroll
    for (int j = 0; j < 8; ++j) {
      float f = (float)v[j];
      s[j] += f;
      s2[j] += f * f;
    }
  }
#pragma unroll
  for (int j = 0; j < 8; ++j) sh[rs][cg + j] = s[j];
  __syncthreads();
  float tot = 0.f;
#pragma unroll
  for (int k = 0; k < 8; ++k) tot += sh[k][t];
  atomicAdd(&sums[t], tot);
  __syncthreads();
#pragma unroll
  for (int j = 0; j < 8; ++j) sh[rs][cg + j] = s2[j];
  __syncthreads();
  tot = 0.f;
#pragma unroll
  for (int k = 0; k < 8; ++k) tot += sh[k][t];
  atomicAdd(&sums[256 + t], tot);
}

// ---------------- launch ----------------

extern "C" void kernel_launch(void* const* d_in, const int* in_sizes, int n_in,
                              void* d_out, int out_size, void* d_ws, size_t ws_size,
                              hipStream_t stream) {
  const float* x = (const float*)d_in[0];
  const int* ei = (const int*)d_in[1];
  const float* ew = (const float*)d_in[2];
  const float* W1 = (const float*)d_in[3];
  const float* b1 = (const float*)d_in[4];
  const float* W2 = (const float*)d_in[5];
  const float* b2 = (const float*)d_in[6];
  const float* W3 = (const float*)d_in[7];
  const float* b3 = (const float*)d_in[8];
  float* out = (float*)d_out;

  const int N = in_sizes[0] / 512;  // 100000
  const int E = in_sizes[2];        // 3200000

  const int NB = (N + 255) >> BSH;
  const int NBLK = (E + EPB - 1) / EPB;
  const int scanN = NB * NBLK;

  char* p = (char*)d_ws;
  auto alloc = [&](size_t bytes) {
    void* r = (void*)p;
    p += (bytes + 255) & ~(size_t)255;
    return r;
  };
  int* rowptr = (int*)alloc((size_t)(N + 1) * 4);
  int* cnt2d = (int*)alloc((size_t)scanN * 4);
  int* off2d = (int*)alloc((size_t)(scanN + 1) * 4);
  int* bsum = (int*)alloc(4096);
  float* statZ = (float*)alloc(1536 * 4);
  float* sumsA = statZ;
  float* sumsB = statZ + 512;
  float* biasRowA = statZ + 1024;
  float* biasRowB = statZ + 1280;
  f16* Wt1 = (f16*)alloc((size_t)512 * 256 * 2);
  f16* Wt2 = (f16*)alloc((size_t)256 * 256 * 2);
  f16* Wt3 = (f16*)alloc((size_t)256 * 64 * 2);
  int2* temp = (int2*)alloc((size_t)E * 8);
  int2* ed = (int2*)alloc((size_t)E * 8);
  f16* sup = (f16*)alloc((size_t)N * 256 * 2);
  f16* act = (f16*)alloc((size_t)N * 256 * 2);

  const int* rows = ei;
  const int* colsIn = ei + E;

  // --- CSR build front: hist + Wt1 conversion in ONE dispatch ---
  const int convBlocks = (512 * 256 + 255) / 256;
  k_hist_convW<<<NBLK + convBlocks, 256, 0, stream>>>(
      rows, cnt2d, E, NBLK, NB, W1, Wt1, 512, 256, statZ);
  int nbs = (scanN + 1023) / 1024;
  k_scan1<<<nbs, 256, 0, stream>>>(cnt2d, off2d, bsum, scanN);
  k_scan2<<<1, 256, 0, stream>>>(bsum, nbs);
  k_scan3<<<nbs, 256, 0, stream>>>(off2d, bsum, scanN, E);
  k_bin<<<NBLK, 256, 0, stream>>>(rows, colsIn, ew, off2d, temp, E, NBLK, NB);
  k_scatter<<<NB, 256, 0, stream>>>(temp, off2d, rowptr, ed, N, E, NBLK, NB);

  const int gemmBlocks = (N + 127) / 128;
  const int aggBlocks = (N * 64 + THREADS - 1) / THREADS;

  // --- Layer 1 ---
  k_gemm_mfma<256, false><<<gemmBlocks, 256, 0, stream>>>(x, Wt1, nullptr, sup, N, 512);
  k_agg256<<<aggBlocks, 256, 0, stream>>>(sup, rowptr, ed, b1, act, N);

  // --- BN1 + fold into W2 ---
  k_colstats<<<240, 256, 0, stream>>>(act, sumsA, N);
  k_bnfold<<<(256 * 256 + 255) / 256, 256, 0, stream>>>(W2, sumsA, Wt2, biasRowA, 256, 256, N);

  // --- Layer 2 ---
  k_gemm_mfma<256, true><<<gemmBlocks, 256, 0, stream>>>(act, Wt2, biasRowA, sup, N, 256);
  k_agg256<<<aggBlocks, 256, 0, stream>>>(sup, rowptr, ed, b2, act, N);

  // --- BN2 + fold into W3 ---
  k_colstats<<<240, 256, 0, stream>>>(act, sumsB, N);
  k_bnfold<<<(256 * 64 + 255) / 256, 256, 0, stream>>>(W3, sumsB, Wt3, biasRowB, 256, 64, N);

  // --- Layer 3 ---
  k_gemm_mfma<64, true><<<gemmBlocks, 256, 0, stream>>>(act, Wt3, biasRowB, sup, N, 256);
  k_agg64<<<aggBlocks, 256, 0, stream>>>(sup, rowptr, ed, b3, out, N);
}

// Round 12
// 875.177 us; speedup vs baseline: 1.0545x; 1.0108x over previous
//
#include <hip/hip_runtime.h>

#define THREADS 256
#define BSH 7        // rows per bucket = 128
#define EPB 8192     // edges per binning block (256 threads x 32)

typedef _Float16 f16;
typedef _Float16 f16x8 __attribute__((ext_vector_type(8)));
typedef _Float16 f16x4 __attribute__((ext_vector_type(4)));
typedef float f32x4 __attribute__((ext_vector_type(4)));

// ---------------- CSR build front + layer-1 weight prep (merged) ----------------
// blocks [0, nblk): per-(bucket, block) histogram
// blocks [nblk, ...): Wt1 transpose/convert; first conv block zeroes stat + scan-status bufs

__global__ __launch_bounds__(256) void k_hist_convW(
    const int* __restrict__ rows, int* __restrict__ cnt2d, int e, int nblk, int nb,
    const float* __restrict__ W, f16* __restrict__ Wt, int K, int N,
    float* __restrict__ statZero, unsigned long long* __restrict__ tpub, int ntiles) {
  int t = threadIdx.x;
  if (blockIdx.x < nblk) {
    __shared__ int hist[1024];
    int blk = blockIdx.x;
    for (int i = t; i < nb; i += 256) hist[i] = 0;
    __syncthreads();
    int eb = blk * EPB;
#pragma unroll 4
    for (int it = 0; it < 32; ++it) {
      int i = eb + it * 256 + t;
      if (i < e) atomicAdd(&hist[rows[i] >> BSH], 1);
    }
    __syncthreads();
    for (int i = t; i < nb; i += 256) cnt2d[i * nblk + blk] = hist[i];
  } else {
    int cb = blockIdx.x - nblk;
    if (cb == 0) {
#pragma unroll
      for (int j = 0; j < 6; ++j) statZero[j * 256 + t] = 0.f;
      for (int i = t; i < ntiles; i += 256) tpub[i] = 0ULL;
    }
    int i = cb * 256 + t;
    if (i < N * K) {
      int n = i / K, k = i - n * K;
      Wt[i] = (f16)W[(size_t)k * N + n];
    }
  }
}

// ---------------- single-pass decoupled-lookback exclusive scan ----------------
// tpub[tile] = (value << 2) | status; status: 0 invalid, 1 aggregate, 2 inclusive-prefix

__global__ __launch_bounds__(256) void k_scanDL(
    const int* __restrict__ cnt, int* __restrict__ outp,
    unsigned long long* __restrict__ tpub, int n) {
  __shared__ int sh[256];
  __shared__ int sPrefix;
  int tile = blockIdx.x, t = threadIdx.x;
  int base = tile * 1024 + t * 4;
  int v[4];
#pragma unroll
  for (int j = 0; j < 4; ++j) {
    int idx = base + j;
    v[j] = (idx < n) ? cnt[idx] : 0;
  }
  int tot = v[0] + v[1] + v[2] + v[3];
  sh[t] = tot;
  __syncthreads();
  for (int off = 1; off < 256; off <<= 1) {
    int x = 0;
    if (t >= off) x = sh[t - off];
    __syncthreads();
    sh[t] += x;
    __syncthreads();
  }
  int blockTot = sh[255];
  int run = sh[t] - tot;  // exclusive within block

  if (t == 0) {
    if (tile == 0) {
      sPrefix = 0;
      atomicExch(&tpub[0], ((unsigned long long)(unsigned)blockTot << 2) | 2ULL);
    } else {
      atomicExch(&tpub[tile], ((unsigned long long)(unsigned)blockTot << 2) | 1ULL);
      long long sum = 0;
      int pred = tile - 1;
      while (true) {
        unsigned long long s = atomicAdd(&tpub[pred], 0ULL);
        unsigned st = (unsigned)(s & 3ULL);
        if (st == 2) { sum += (long long)(s >> 2); break; }
        if (st == 1) { sum += (long long)(s >> 2); --pred; }
      }
      sPrefix = (int)sum;
      atomicExch(&tpub[tile],
                 ((unsigned long long)(unsigned)(sum + blockTot) << 2) | 2ULL);
    }
  }
  __syncthreads();
  int pfx = sPrefix;
#pragma unroll
  for (int j = 0; j < 4; ++j) {
    int idx = base + j;
    if (idx < n) outp[idx] = run + pfx;
    run += v[j];
  }
  if (tile == gridDim.x - 1 && t == 0) outp[n] = pfx + blockTot;
}

// ---------------- GEMM device body (shared by wrappers + merged kernel) ----------------
// Csup[M][BN] = A[M][K] @ Wt^T + biasRow, f16 out. BM=128, 4 waves.

template <int BN, bool AF16>
__device__ __forceinline__ void gemm_dev(
    int mblk, const void* __restrict__ Ap, const f16* __restrict__ Wt,
    const float* __restrict__ biasRow, f16* __restrict__ Csup, int M, int K,
    char* smem) {
  constexpr int BM = 128;
  constexpr int BK = 32;
  constexpr int LDT = BK + 8;
  f16 (*As)[LDT] = (f16(*)[LDT])smem;
  f16 (*Bs)[LDT] = (f16(*)[LDT])(smem + BM * LDT * 2);

  const int tid = threadIdx.x;
  const int wave = tid >> 6;
  const int lane = tid & 63;
  const int m0 = mblk * BM;
  constexpr int WM = (BN == 256) ? 8 : 2;
  constexpr int WN = 4;
  const int wrow = (BN == 256) ? 0 : wave * 32;
  const int wcol = (BN == 256) ? wave * 64 : 0;
  const int l15 = lane & 15;
  const int lq = lane >> 4;

  const int arow = tid >> 1;
  const int akofs = (tid & 1) * 16;
  const int srow = tid >> 2;
  const int skofs = (tid & 3) * 8;
  constexpr int BROWS = BN / 64;

  f32x4 acc[WM][WN] = {};

  for (int k0 = 0; k0 < K; k0 += BK) {
    f16x8 a16[2];
    int gr = m0 + arow;
    if constexpr (AF16) {
      if (gr < M) {
        const f16* ap = (const f16*)Ap + (size_t)gr * K + k0 + akofs;
        a16[0] = *(const f16x8*)ap;
        a16[1] = *(const f16x8*)(ap + 8);
      } else {
#pragma unroll
        for (int j = 0; j < 8; ++j) { a16[0][j] = (f16)0.f; a16[1][j] = (f16)0.f; }
      }
    } else {
      float va[16];
      if (gr < M) {
        const float* ap = (const float*)Ap + (size_t)gr * K + k0 + akofs;
#pragma unroll
        for (int q = 0; q < 4; ++q) *(float4*)&va[q * 4] = *(const float4*)(ap + q * 4);
      } else {
#pragma unroll
        for (int j = 0; j < 16; ++j) va[j] = 0.f;
      }
#pragma unroll
      for (int j = 0; j < 8; ++j) { a16[0][j] = (f16)va[j]; a16[1][j] = (f16)va[8 + j]; }
    }

    f16x8 vb[BROWS];
#pragma unroll
    for (int j = 0; j < BROWS; ++j)
      vb[j] = *(const f16x8*)(Wt + (size_t)(srow + j * 64) * K + k0 + skofs);

    __syncthreads();
    *(f16x8*)&As[arow][akofs] = a16[0];
    *(f16x8*)&As[arow][akofs + 8] = a16[1];
#pragma unroll
    for (int j = 0; j < BROWS; ++j) *(f16x8*)&Bs[srow + j * 64][skofs] = vb[j];
    __syncthreads();

    f16x8 af[WM], bf[WN];
#pragma unroll
    for (int m = 0; m < WM; ++m)
      af[m] = *(const f16x8*)&As[wrow + m * 16 + l15][lq * 8];
#pragma unroll
    for (int n = 0; n < WN; ++n)
      bf[n] = *(const f16x8*)&Bs[wcol + n * 16 + l15][lq * 8];
#pragma unroll
    for (int m = 0; m < WM; ++m)
#pragma unroll
      for (int n = 0; n < WN; ++n)
        acc[m][n] = __builtin_amdgcn_mfma_f32_16x16x32_f16(af[m], bf[n], acc[m][n], 0, 0, 0);
  }

  float bb[WN];
#pragma unroll
  for (int n = 0; n < WN; ++n)
    bb[n] = biasRow ? biasRow[wcol + n * 16 + l15] : 0.f;

#pragma unroll
  for (int m = 0; m < WM; ++m) {
#pragma unroll
    for (int r = 0; r < 4; ++r) {
      int row = m0 + wrow + m * 16 + lq * 4 + r;
      if (row < M) {
        f16* cp = Csup + (size_t)row * BN + wcol + l15;
#pragma unroll
        for (int n = 0; n < WN; ++n) cp[n * 16] = (f16)(acc[m][n][r] + bb[n]);
      }
    }
  }
}

template <int BN, bool AF16>
__global__ __launch_bounds__(256) void k_gemm_mfma(
    const void* __restrict__ Ap, const f16* __restrict__ Wt,
    const float* __restrict__ biasRow, f16* __restrict__ Csup, int M, int K) {
  __shared__ __align__(16) char smem[(128 + BN) * 40 * 2];
  gemm_dev<BN, AF16>(blockIdx.x, Ap, Wt, biasRow, Csup, M, K, smem);
}

// ---------------- merged: k_bin (blocks < nblk) + layer-1 GEMM (rest) ----------------

__global__ __launch_bounds__(256) void k_bin_gemm(
    const int* __restrict__ rows, const int* __restrict__ cols,
    const float* __restrict__ w, const int* __restrict__ off2d,
    int2* __restrict__ temp, int e, int nblk, int nb,
    const float* __restrict__ x, const f16* __restrict__ Wt1,
    f16* __restrict__ sup, int M) {
  __shared__ __align__(16) char smem[(128 + 256) * 40 * 2];
  int t = threadIdx.x;
  if (blockIdx.x < nblk) {
    int* base = (int*)smem;          // [1024]
    int* cursor = (int*)smem + 1024; // [1024]
    int blk = blockIdx.x;
    for (int i = t; i < nb; i += 256) {
      base[i] = off2d[i * nblk + blk];
      cursor[i] = 0;
    }
    __syncthreads();
    int eb = blk * EPB;
#pragma unroll 4
    for (int it = 0; it < 32; ++it) {
      int i = eb + it * 256 + t;
      if (i < e) {
        int r = rows[i];
        int b = r >> BSH;
        int pos = base[b] + atomicAdd(&cursor[b], 1);
        temp[pos] = make_int2(((r & 127) << 17) | cols[i], __float_as_int(w[i]));
      }
    }
  } else {
    gemm_dev<256, false>(blockIdx.x - nblk, x, Wt1, nullptr, sup, M, 512, smem);
  }
}

// ---------------- scatter: one block per 128-row bucket ----------------

__global__ __launch_bounds__(256) void k_scatter(
    const int2* __restrict__ temp, const int* __restrict__ off2d,
    int* __restrict__ rowptr, int2* __restrict__ ed,
    int n, int e, int nblk, int nb) {
  __shared__ int rowCnt[128];
  __shared__ int rowBase[128];
  __shared__ int rowCur[128];
  int b = blockIdx.x, t = threadIdx.x;
  int r0 = b << BSH;
  int nr = min(128, n - r0);
  int start = off2d[b * nblk];
  int end = off2d[(b + 1) * nblk];
  if (t < 128) rowCnt[t] = 0;
  __syncthreads();
  for (int p = start + t; p < end; p += 256)
    atomicAdd(&rowCnt[temp[p].x >> 17], 1);
  __syncthreads();
  int v = 0;
  if (t < 128) {
    v = rowCnt[t];
    rowBase[t] = v;
  }
  __syncthreads();
  for (int off = 1; off < 128; off <<= 1) {
    int x = 0;
    if (t < 128 && t >= off) x = rowBase[t - off];
    __syncthreads();
    if (t < 128) rowBase[t] += x;
    __syncthreads();
  }
  if (t < 128) {
    int excl = rowBase[t] - v;
    rowBase[t] = excl;
    rowCur[t] = 0;
    if (t < nr) rowptr[r0 + t] = start + excl;
  }
  if (b == nb - 1 && t == 0) rowptr[n] = e;
  __syncthreads();
  for (int p = start + t; p < end; p += 256) {
    int2 ei = temp[p];
    int ro = ei.x >> 17;
    int slot = start + rowBase[ro] + atomicAdd(&rowCur[ro], 1);
    ed[slot] = make_int2(ei.x & 0x1FFFF, ei.y);
  }
}

// ---------------- Fused BN-param + W-fold + bias-fold ----------------

__global__ __launch_bounds__(256) void k_bnfold(
    const float* __restrict__ W, const float* __restrict__ sums,
    f16* __restrict__ Wt, float* __restrict__ biasRow, int K, int N, int n) {
  __shared__ float sc[256], sf[256];
  int t = threadIdx.x;
  if (t < K) {
    float inv = 1.0f / (float)n;
    float mean = sums[t] * inv;
    float var = sums[256 + t] * inv - mean * mean;
    float rstd = rsqrtf(var + 1e-5f);
    sc[t] = rstd;
    sf[t] = -mean * rstd;
  }
  __syncthreads();
  int i = blockIdx.x * 256 + t;
  if (i < N * K) {
    int nn = i / K, k = i - nn * K;
    Wt[i] = (f16)(sc[k] * W[(size_t)k * N + nn]);
  }
  if (blockIdx.x < (K >> 4) && t < N) {
    int k0 = blockIdx.x * 16;
    float s = 0.f;
#pragma unroll
    for (int j = 0; j < 16; ++j) s += sf[k0 + j] * W[(size_t)(k0 + j) * N + t];
    atomicAdd(&biasRow[t], s);
  }
}

// ---------------- Aggregation D=256: one WAVE per row, 16-deep gather pipeline ----

__global__ __launch_bounds__(256) void k_agg256(
    const f16* __restrict__ sup, const int* __restrict__ rowptr,
    const int2* __restrict__ ed, const float* __restrict__ bias,
    f16* __restrict__ out, int n) {
  int wid = (blockIdx.x * THREADS + threadIdx.x) >> 6;
  int lane = threadIdx.x & 63;
  if (wid >= n) return;
  int p0 = rowptr[wid], p1 = rowptr[wid + 1];

  const f16x4* supv = (const f16x4*)sup;
  float acc[4][4] = {};
  int p = p0;
  for (; p + 16 <= p1; p += 16) {
    int2 e[16];
#pragma unroll
    for (int j = 0; j < 16; ++j) e[j] = ed[p + j];
    f16x4 v[16];
#pragma unroll
    for (int j = 0; j < 16; ++j) v[j] = supv[(size_t)e[j].x * 64 + lane];
#pragma unroll
    for (int j = 0; j < 16; ++j) {
      float wt = __int_as_float(e[j].y);
      acc[j & 3][0] += wt * (float)v[j][0];
      acc[j & 3][1] += wt * (float)v[j][1];
      acc[j & 3][2] += wt * (float)v[j][2];
      acc[j & 3][3] += wt * (float)v[j][3];
    }
  }
  for (; p + 4 <= p1; p += 4) {
    int2 e[4];
#pragma unroll
    for (int j = 0; j < 4; ++j) e[j] = ed[p + j];
    f16x4 v[4];
#pragma unroll
    for (int j = 0; j < 4; ++j) v[j] = supv[(size_t)e[j].x * 64 + lane];
#pragma unroll
    for (int j = 0; j < 4; ++j) {
      float wt = __int_as_float(e[j].y);
      acc[j][0] += wt * (float)v[j][0];
      acc[j][1] += wt * (float)v[j][1];
      acc[j][2] += wt * (float)v[j][2];
      acc[j][3] += wt * (float)v[j][3];
    }
  }
  for (; p < p1; ++p) {
    int2 e0 = ed[p];
    float wt = __int_as_float(e0.y);
    f16x4 v = supv[(size_t)e0.x * 64 + lane];
    acc[0][0] += wt * (float)v[0];
    acc[0][1] += wt * (float)v[1];
    acc[0][2] += wt * (float)v[2];
    acc[0][3] += wt * (float)v[3];
  }
  float4 b = *(const float4*)(bias + lane * 4);
  f16x4 r;
  r[0] = (f16)fmaxf(acc[0][0] + acc[1][0] + acc[2][0] + acc[3][0] + b.x, 0.f);
  r[1] = (f16)fmaxf(acc[0][1] + acc[1][1] + acc[2][1] + acc[3][1] + b.y, 0.f);
  r[2] = (f16)fmaxf(acc[0][2] + acc[1][2] + acc[2][2] + acc[3][2] + b.z, 0.f);
  r[3] = (f16)fmaxf(acc[0][3] + acc[1][3] + acc[2][3] + acc[3][3] + b.w, 0.f);
  *(f16x4*)(out + (size_t)wid * 256 + lane * 4) = r;
}

// ---------------- Aggregation D=64: one WAVE per row, quarter-wave edge slots ----

__global__ __launch_bounds__(256) void k_agg64(
    const f16* __restrict__ sup, const int* __restrict__ rowptr,
    const int2* __restrict__ ed, const float* __restrict__ bias,
    float* __restrict__ out, int n) {
  int wid = (blockIdx.x * THREADS + threadIdx.x) >> 6;
  int lane = threadIdx.x & 63;
  if (wid >= n) return;
  int p0 = rowptr[wid], p1 = rowptr[wid + 1];
  int q = lane >> 4;    // edge slot 0..3
  int hl = lane & 15;   // col group of 4

  const f16x4* supv = (const f16x4*)sup;
  float acc[2][4] = {};
  int p = p0;
  for (; p + 32 <= p1; p += 32) {
    int2 e[8];
#pragma unroll
    for (int j = 0; j < 8; ++j) e[j] = ed[p + 4 * j + q];
    f16x4 v[8];
#pragma unroll
    for (int j = 0; j < 8; ++j) v[j] = supv[(size_t)e[j].x * 16 + hl];
#pragma unroll
    for (int j = 0; j < 8; ++j) {
      float wt = __int_as_float(e[j].y);
      acc[j & 1][0] += wt * (float)v[j][0];
      acc[j & 1][1] += wt * (float)v[j][1];
      acc[j & 1][2] += wt * (float)v[j][2];
      acc[j & 1][3] += wt * (float)v[j][3];
    }
  }
  for (; p + 4 <= p1; p += 4) {
    int2 e0 = ed[p + q];
    float wt = __int_as_float(e0.y);
    f16x4 v = supv[(size_t)e0.x * 16 + hl];
    acc[0][0] += wt * (float)v[0];
    acc[0][1] += wt * (float)v[1];
    acc[0][2] += wt * (float)v[2];
    acc[0][3] += wt * (float)v[3];
  }
  if (p < p1) {
    int idx = p + q;
    int c = 0;
    float wt = 0.f;
    if (idx < p1) {
      int2 e0 = ed[idx];
      c = e0.x;
      wt = __int_as_float(e0.y);
    }
    f16x4 v = supv[(size_t)c * 16 + hl];
    acc[0][0] += wt * (float)v[0];
    acc[0][1] += wt * (float)v[1];
    acc[0][2] += wt * (float)v[2];
    acc[0][3] += wt * (float)v[3];
  }
  float t0 = acc[0][0] + acc[1][0];
  float t1 = acc[0][1] + acc[1][1];
  float t2 = acc[0][2] + acc[1][2];
  float t3 = acc[0][3] + acc[1][3];
  t0 += __shfl_xor(t0, 16); t0 += __shfl_xor(t0, 32);
  t1 += __shfl_xor(t1, 16); t1 += __shfl_xor(t1, 32);
  t2 += __shfl_xor(t2, 16); t2 += __shfl_xor(t2, 32);
  t3 += __shfl_xor(t3, 16); t3 += __shfl_xor(t3, 32);
  if (q == 0) {
    float4 b = *(const float4*)(bias + hl * 4);
    float4 res;
    res.x = fmaxf(t0 + b.x, 0.f);
    res.y = fmaxf(t1 + b.y, 0.f);
    res.z = fmaxf(t2 + b.z, 0.f);
    res.w = fmaxf(t3 + b.w, 0.f);
    *(float4*)(out + (size_t)wid * 64 + hl * 4) = res;
  }
}

// ---------------- BN stats ----------------

__global__ __launch_bounds__(256) void k_colstats(const f16* __restrict__ y,
                                                  float* __restrict__ sums, int n) {
  __shared__ float sh[8][256];
  int t = threadIdx.x;
  int cg = (t & 31) * 8;
  int rs = t >> 5;
  float s[8] = {}, s2[8] = {};
  for (int r = blockIdx.x * 8 + rs; r < n; r += gridDim.x * 8) {
    f16x8 v = *(const f16x8*)(y + (size_t)r * 256 + cg);
#pragma unroll
    for (int j = 0; j < 8; ++j) {
      float f = (float)v[j];
      s[j] += f;
      s2[j] += f * f;
    }
  }
#pragma unroll
  for (int j = 0; j < 8; ++j) sh[rs][cg + j] = s[j];
  __syncthreads();
  float tot = 0.f;
#pragma unroll
  for (int k = 0; k < 8; ++k) tot += sh[k][t];
  atomicAdd(&sums[t], tot);
  __syncthreads();
#pragma unroll
  for (int j = 0; j < 8; ++j) sh[rs][cg + j] = s2[j];
  __syncthreads();
  tot = 0.f;
#pragma unroll
  for (int k = 0; k < 8; ++k) tot += sh[k][t];
  atomicAdd(&sums[256 + t], tot);
}

// ---------------- launch ----------------

extern "C" void kernel_launch(void* const* d_in, const int* in_sizes, int n_in,
                              void* d_out, int out_size, void* d_ws, size_t ws_size,
                              hipStream_t stream) {
  const float* x = (const float*)d_in[0];
  const int* ei = (const int*)d_in[1];
  const float* ew = (const float*)d_in[2];
  const float* W1 = (const float*)d_in[3];
  const float* b1 = (const float*)d_in[4];
  const float* W2 = (const float*)d_in[5];
  const float* b2 = (const float*)d_in[6];
  const float* W3 = (const float*)d_in[7];
  const float* b3 = (const float*)d_in[8];
  float* out = (float*)d_out;

  const int N = in_sizes[0] / 512;  // 100000
  const int E = in_sizes[2];        // 3200000

  const int NB = (N + 127) >> BSH;            // 128-row buckets (782)
  const int NBLK = (E + EPB - 1) / EPB;       // binning blocks (391)
  const int scanN = NB * NBLK;
  const int ntiles = (scanN + 1023) / 1024;

  char* p = (char*)d_ws;
  auto alloc = [&](size_t bytes) {
    void* r = (void*)p;
    p += (bytes + 255) & ~(size_t)255;
    return r;
  };
  int* rowptr = (int*)alloc((size_t)(N + 1) * 4);
  int* cnt2d = (int*)alloc((size_t)scanN * 4);
  int* off2d = (int*)alloc((size_t)(scanN + 1) * 4);
  unsigned long long* tpub = (unsigned long long*)alloc((size_t)ntiles * 8);
  float* statZ = (float*)alloc(1536 * 4);
  float* sumsA = statZ;
  float* sumsB = statZ + 512;
  float* biasRowA = statZ + 1024;
  float* biasRowB = statZ + 1280;
  f16* Wt1 = (f16*)alloc((size_t)512 * 256 * 2);
  f16* Wt2 = (f16*)alloc((size_t)256 * 256 * 2);
  f16* Wt3 = (f16*)alloc((size_t)256 * 64 * 2);
  int2* temp = (int2*)alloc((size_t)E * 8);
  int2* ed = (int2*)alloc((size_t)E * 8);
  f16* sup = (f16*)alloc((size_t)N * 256 * 2);
  f16* act = (f16*)alloc((size_t)N * 256 * 2);

  const int* rows = ei;
  const int* colsIn = ei + E;

  const int gemmBlocks = (N + 127) / 128;
  const int aggBlocks = (N * 64 + THREADS - 1) / THREADS;
  const int convBlocks = (512 * 256 + 255) / 256;

  // --- front: hist + Wt1 convert + zero stats/scan-status (1 dispatch) ---
  k_hist_convW<<<NBLK + convBlocks, 256, 0, stream>>>(
      rows, cnt2d, E, NBLK, NB, W1, Wt1, 512, 256, statZ, tpub, ntiles);

  // --- single-pass scan ---
  k_scanDL<<<ntiles, 256, 0, stream>>>(cnt2d, off2d, tpub, scanN);

  // --- bin + layer-1 GEMM (1 dispatch, independent halves) ---
  k_bin_gemm<<<NBLK + gemmBlocks, 256, 0, stream>>>(
      rows, colsIn, ew, off2d, temp, E, NBLK, NB, x, Wt1, sup, N);

  // --- scatter into final CSR ---
  k_scatter<<<NB, 256, 0, stream>>>(temp, off2d, rowptr, ed, N, E, NBLK, NB);

  // --- Layer 1 aggregation ---
  k_agg256<<<aggBlocks, 256, 0, stream>>>(sup, rowptr, ed, b1, act, N);

  // --- BN1 + fold into W2 ---
  k_colstats<<<240, 256, 0, stream>>>(act, sumsA, N);
  k_bnfold<<<(256 * 256 + 255) / 256, 256, 0, stream>>>(W2, sumsA, Wt2, biasRowA, 256, 256, N);

  // --- Layer 2 ---
  k_gemm_mfma<256, true><<<gemmBlocks, 256, 0, stream>>>(act, Wt2, biasRowA, sup, N, 256);
  k_agg256<<<aggBlocks, 256, 0, stream>>>(sup, rowptr, ed, b2, act, N);

  // --- BN2 + fold into W3 ---
  k_colstats<<<240, 256, 0, stream>>>(act, sumsB, N);
  k_bnfold<<<(256 * 64 + 255) / 256, 256, 0, stream>>>(W3, sumsB, Wt3, biasRowB, 256, 64, N);

  // --- Layer 3 ---
  k_gemm_mfma<64, true><<<gemmBlocks, 256, 0, stream>>>(act, Wt3, biasRowB, sup, N, 256);
  k_agg64<<<aggBlocks, 256, 0, stream>>>(sup, rowptr, ed, b3, out, N);
}

// Round 13
// 871.525 us; speedup vs baseline: 1.0589x; 1.0042x over previous
//
#include <hip/hip_runtime.h>

#define THREADS 256
#define BSH 7        // rows per bucket = 128
#define EPB 8192     // edges per binning block (256 threads x 32)

typedef _Float16 f16;
typedef _Float16 f16x8 __attribute__((ext_vector_type(8)));
typedef _Float16 f16x4 __attribute__((ext_vector_type(4)));
typedef float f32x4 __attribute__((ext_vector_type(4)));

// ---------------- CSR build front + layer-1 weight prep (merged) ----------------
// blocks [0, nblk): per-(bucket, block) histogram
// blocks [nblk, ...): Wt1 transpose/convert; first conv block zeroes stat + scan-status bufs

__global__ __launch_bounds__(256) void k_hist_convW(
    const int* __restrict__ rows, int* __restrict__ cnt2d, int e, int nblk, int nb,
    const float* __restrict__ W, f16* __restrict__ Wt, int K, int N,
    float* __restrict__ statZero, unsigned long long* __restrict__ tpub, int ntiles) {
  int t = threadIdx.x;
  if (blockIdx.x < nblk) {
    __shared__ int hist[1024];
    int blk = blockIdx.x;
    for (int i = t; i < nb; i += 256) hist[i] = 0;
    __syncthreads();
    int eb = blk * EPB;
#pragma unroll 4
    for (int it = 0; it < 32; ++it) {
      int i = eb + it * 256 + t;
      if (i < e) atomicAdd(&hist[rows[i] >> BSH], 1);
    }
    __syncthreads();
    for (int i = t; i < nb; i += 256) cnt2d[i * nblk + blk] = hist[i];
  } else {
    int cb = blockIdx.x - nblk;
    if (cb == 0) {
#pragma unroll
      for (int j = 0; j < 6; ++j) statZero[j * 256 + t] = 0.f;
      for (int i = t; i < ntiles; i += 256) tpub[i] = 0ULL;
    }
    int i = cb * 256 + t;
    if (i < N * K) {
      int n = i / K, k = i - n * K;
      Wt[i] = (f16)W[(size_t)k * N + n];
    }
  }
}

// ---------------- single-pass decoupled-lookback exclusive scan ----------------
// tpub[tile] = (value << 2) | status; status: 0 invalid, 1 aggregate, 2 inclusive-prefix

__global__ __launch_bounds__(256) void k_scanDL(
    const int* __restrict__ cnt, int* __restrict__ outp,
    unsigned long long* __restrict__ tpub, int n) {
  __shared__ int sh[256];
  __shared__ int sPrefix;
  int tile = blockIdx.x, t = threadIdx.x;
  int base = tile * 1024 + t * 4;
  int v[4];
#pragma unroll
  for (int j = 0; j < 4; ++j) {
    int idx = base + j;
    v[j] = (idx < n) ? cnt[idx] : 0;
  }
  int tot = v[0] + v[1] + v[2] + v[3];
  sh[t] = tot;
  __syncthreads();
  for (int off = 1; off < 256; off <<= 1) {
    int x = 0;
    if (t >= off) x = sh[t - off];
    __syncthreads();
    sh[t] += x;
    __syncthreads();
  }
  int blockTot = sh[255];
  int run = sh[t] - tot;  // exclusive within block

  if (t == 0) {
    if (tile == 0) {
      sPrefix = 0;
      atomicExch(&tpub[0], ((unsigned long long)(unsigned)blockTot << 2) | 2ULL);
    } else {
      atomicExch(&tpub[tile], ((unsigned long long)(unsigned)blockTot << 2) | 1ULL);
      long long sum = 0;
      int pred = tile - 1;
      while (true) {
        unsigned long long s = atomicAdd(&tpub[pred], 0ULL);
        unsigned st = (unsigned)(s & 3ULL);
        if (st == 2) { sum += (long long)(s >> 2); break; }
        if (st == 1) { sum += (long long)(s >> 2); --pred; }
      }
      sPrefix = (int)sum;
      atomicExch(&tpub[tile],
                 ((unsigned long long)(unsigned)(sum + blockTot) << 2) | 2ULL);
    }
  }
  __syncthreads();
  int pfx = sPrefix;
#pragma unroll
  for (int j = 0; j < 4; ++j) {
    int idx = base + j;
    if (idx < n) outp[idx] = run + pfx;
    run += v[j];
  }
  if (tile == gridDim.x - 1 && t == 0) outp[n] = pfx + blockTot;
}

// ---------------- GEMM device body (shared by wrappers + merged kernel) ----------------
// Csup[M][BN] = A[M][K] @ Wt^T + biasRow, f16 out. BM=128, 4 waves.

template <int BN, bool AF16>
__device__ __forceinline__ void gemm_dev(
    int mblk, const void* __restrict__ Ap, const f16* __restrict__ Wt,
    const float* __restrict__ biasRow, f16* __restrict__ Csup, int M, int K,
    char* smem) {
  constexpr int BM = 128;
  constexpr int BK = 32;
  constexpr int LDT = BK + 8;
  f16 (*As)[LDT] = (f16(*)[LDT])smem;
  f16 (*Bs)[LDT] = (f16(*)[LDT])(smem + BM * LDT * 2);

  const int tid = threadIdx.x;
  const int wave = tid >> 6;
  const int lane = tid & 63;
  const int m0 = mblk * BM;
  constexpr int WM = (BN == 256) ? 8 : 2;
  constexpr int WN = 4;
  const int wrow = (BN == 256) ? 0 : wave * 32;
  const int wcol = (BN == 256) ? wave * 64 : 0;
  const int l15 = lane & 15;
  const int lq = lane >> 4;

  const int arow = tid >> 1;
  const int akofs = (tid & 1) * 16;
  const int srow = tid >> 2;
  const int skofs = (tid & 3) * 8;
  constexpr int BROWS = BN / 64;

  f32x4 acc[WM][WN] = {};

  for (int k0 = 0; k0 < K; k0 += BK) {
    f16x8 a16[2];
    int gr = m0 + arow;
    if constexpr (AF16) {
      if (gr < M) {
        const f16* ap = (const f16*)Ap + (size_t)gr * K + k0 + akofs;
        a16[0] = *(const f16x8*)ap;
        a16[1] = *(const f16x8*)(ap + 8);
      } else {
#pragma unroll
        for (int j = 0; j < 8; ++j) { a16[0][j] = (f16)0.f; a16[1][j] = (f16)0.f; }
      }
    } else {
      float va[16];
      if (gr < M) {
        const float* ap = (const float*)Ap + (size_t)gr * K + k0 + akofs;
#pragma unroll
        for (int q = 0; q < 4; ++q) *(float4*)&va[q * 4] = *(const float4*)(ap + q * 4);
      } else {
#pragma unroll
        for (int j = 0; j < 16; ++j) va[j] = 0.f;
      }
#pragma unroll
      for (int j = 0; j < 8; ++j) { a16[0][j] = (f16)va[j]; a16[1][j] = (f16)va[8 + j]; }
    }

    f16x8 vb[BROWS];
#pragma unroll
    for (int j = 0; j < BROWS; ++j)
      vb[j] = *(const f16x8*)(Wt + (size_t)(srow + j * 64) * K + k0 + skofs);

    __syncthreads();
    *(f16x8*)&As[arow][akofs] = a16[0];
    *(f16x8*)&As[arow][akofs + 8] = a16[1];
#pragma unroll
    for (int j = 0; j < BROWS; ++j) *(f16x8*)&Bs[srow + j * 64][skofs] = vb[j];
    __syncthreads();

    f16x8 af[WM], bf[WN];
#pragma unroll
    for (int m = 0; m < WM; ++m)
      af[m] = *(const f16x8*)&As[wrow + m * 16 + l15][lq * 8];
#pragma unroll
    for (int n = 0; n < WN; ++n)
      bf[n] = *(const f16x8*)&Bs[wcol + n * 16 + l15][lq * 8];
#pragma unroll
    for (int m = 0; m < WM; ++m)
#pragma unroll
      for (int n = 0; n < WN; ++n)
        acc[m][n] = __builtin_amdgcn_mfma_f32_16x16x32_f16(af[m], bf[n], acc[m][n], 0, 0, 0);
  }

  float bb[WN];
#pragma unroll
  for (int n = 0; n < WN; ++n)
    bb[n] = biasRow ? biasRow[wcol + n * 16 + l15] : 0.f;

#pragma unroll
  for (int m = 0; m < WM; ++m) {
#pragma unroll
    for (int r = 0; r < 4; ++r) {
      int row = m0 + wrow + m * 16 + lq * 4 + r;
      if (row < M) {
        f16* cp = Csup + (size_t)row * BN + wcol + l15;
#pragma unroll
        for (int n = 0; n < WN; ++n) cp[n * 16] = (f16)(acc[m][n][r] + bb[n]);
      }
    }
  }
}

template <int BN, bool AF16>
__global__ __launch_bounds__(256) void k_gemm_mfma(
    const void* __restrict__ Ap, const f16* __restrict__ Wt,
    const float* __restrict__ biasRow, f16* __restrict__ Csup, int M, int K) {
  __shared__ __align__(16) char smem[(128 + BN) * 40 * 2];
  gemm_dev<BN, AF16>(blockIdx.x, Ap, Wt, biasRow, Csup, M, K, smem);
}

// ---------------- merged: k_bin (blocks < nblk) + layer-1 GEMM (rest) ----------------

__global__ __launch_bounds__(256) void k_bin_gemm(
    const int* __restrict__ rows, const int* __restrict__ cols,
    const float* __restrict__ w, const int* __restrict__ off2d,
    int2* __restrict__ temp, int e, int nblk, int nb,
    const float* __restrict__ x, const f16* __restrict__ Wt1,
    f16* __restrict__ sup, int M) {
  __shared__ __align__(16) char smem[(128 + 256) * 40 * 2];
  int t = threadIdx.x;
  if (blockIdx.x < nblk) {
    int* base = (int*)smem;          // [1024]
    int* cursor = (int*)smem + 1024; // [1024]
    int blk = blockIdx.x;
    for (int i = t; i < nb; i += 256) {
      base[i] = off2d[i * nblk + blk];
      cursor[i] = 0;
    }
    __syncthreads();
    int eb = blk * EPB;
#pragma unroll 4
    for (int it = 0; it < 32; ++it) {
      int i = eb + it * 256 + t;
      if (i < e) {
        int r = rows[i];
        int b = r >> BSH;
        int pos = base[b] + atomicAdd(&cursor[b], 1);
        temp[pos] = make_int2(((r & 127) << 17) | cols[i], __float_as_int(w[i]));
      }
    }
  } else {
    gemm_dev<256, false>(blockIdx.x - nblk, x, Wt1, nullptr, sup, M, 512, smem);
  }
}

// ---------------- scatter: one block per 128-row bucket ----------------

__global__ __launch_bounds__(256) void k_scatter(
    const int2* __restrict__ temp, const int* __restrict__ off2d,
    int* __restrict__ rowptr, int2* __restrict__ ed,
    int n, int e, int nblk, int nb) {
  __shared__ int rowCnt[128];
  __shared__ int rowBase[128];
  __shared__ int rowCur[128];
  int b = blockIdx.x, t = threadIdx.x;
  int r0 = b << BSH;
  int nr = min(128, n - r0);
  int start = off2d[b * nblk];
  int end = off2d[(b + 1) * nblk];
  if (t < 128) rowCnt[t] = 0;
  __syncthreads();
  for (int p = start + t; p < end; p += 256)
    atomicAdd(&rowCnt[temp[p].x >> 17], 1);
  __syncthreads();
  int v = 0;
  if (t < 128) {
    v = rowCnt[t];
    rowBase[t] = v;
  }
  __syncthreads();
  for (int off = 1; off < 128; off <<= 1) {
    int x = 0;
    if (t < 128 && t >= off) x = rowBase[t - off];
    __syncthreads();
    if (t < 128) rowBase[t] += x;
    __syncthreads();
  }
  if (t < 128) {
    int excl = rowBase[t] - v;
    rowBase[t] = excl;
    rowCur[t] = 0;
    if (t < nr) rowptr[r0 + t] = start + excl;
  }
  if (b == nb - 1 && t == 0) rowptr[n] = e;
  __syncthreads();
  for (int p = start + t; p < end; p += 256) {
    int2 ei = temp[p];
    int ro = ei.x >> 17;
    int slot = start + rowBase[ro] + atomicAdd(&rowCur[ro], 1);
    ed[slot] = make_int2(ei.x & 0x1FFFF, ei.y);
  }
}

// ---------------- Fused BN-param + W-fold + bias-fold ----------------

__global__ __launch_bounds__(256) void k_bnfold(
    const float* __restrict__ W, const float* __restrict__ sums,
    f16* __restrict__ Wt, float* __restrict__ biasRow, int K, int N, int n) {
  __shared__ float sc[256], sf[256];
  int t = threadIdx.x;
  if (t < K) {
    float inv = 1.0f / (float)n;
    float mean = sums[t] * inv;
    float var = sums[256 + t] * inv - mean * mean;
    float rstd = rsqrtf(var + 1e-5f);
    sc[t] = rstd;
    sf[t] = -mean * rstd;
  }
  __syncthreads();
  int i = blockIdx.x * 256 + t;
  if (i < N * K) {
    int nn = i / K, k = i - nn * K;
    Wt[i] = (f16)(sc[k] * W[(size_t)k * N + nn]);
  }
  if (blockIdx.x < (K >> 4) && t < N) {
    int k0 = blockIdx.x * 16;
    float s = 0.f;
#pragma unroll
    for (int j = 0; j < 16; ++j) s += sf[k0 + j] * W[(size_t)(k0 + j) * N + t];
    atomicAdd(&biasRow[t], s);
  }
}

// ---------------- Aggregation D=256: one WAVE per row, 16-deep gather pipeline ----

__global__ __launch_bounds__(256) void k_agg256(
    const f16* __restrict__ sup, const int* __restrict__ rowptr,
    const int2* __restrict__ ed, const float* __restrict__ bias,
    f16* __restrict__ out, int n) {
  int wid = (blockIdx.x * THREADS + threadIdx.x) >> 6;
  int lane = threadIdx.x & 63;
  if (wid >= n) return;
  int p0 = rowptr[wid], p1 = rowptr[wid + 1];

  const f16x4* supv = (const f16x4*)sup;
  float acc[4][4] = {};
  int p = p0;
  for (; p + 16 <= p1; p += 16) {
    int2 e[16];
#pragma unroll
    for (int j = 0; j < 16; ++j) e[j] = ed[p + j];
    f16x4 v[16];
#pragma unroll
    for (int j = 0; j < 16; ++j) v[j] = supv[(size_t)e[j].x * 64 + lane];
#pragma unroll
    for (int j = 0; j < 16; ++j) {
      float wt = __int_as_float(e[j].y);
      acc[j & 3][0] += wt * (float)v[j][0];
      acc[j & 3][1] += wt * (float)v[j][1];
      acc[j & 3][2] += wt * (float)v[j][2];
      acc[j & 3][3] += wt * (float)v[j][3];
    }
  }
  for (; p + 4 <= p1; p += 4) {
    int2 e[4];
#pragma unroll
    for (int j = 0; j < 4; ++j) e[j] = ed[p + j];
    f16x4 v[4];
#pragma unroll
    for (int j = 0; j < 4; ++j) v[j] = supv[(size_t)e[j].x * 64 + lane];
#pragma unroll
    for (int j = 0; j < 4; ++j) {
      float wt = __int_as_float(e[j].y);
      acc[j][0] += wt * (float)v[j][0];
      acc[j][1] += wt * (float)v[j][1];
      acc[j][2] += wt * (float)v[j][2];
      acc[j][3] += wt * (float)v[j][3];
    }
  }
  for (; p < p1; ++p) {
    int2 e0 = ed[p];
    float wt = __int_as_float(e0.y);
    f16x4 v = supv[(size_t)e0.x * 64 + lane];
    acc[0][0] += wt * (float)v[0];
    acc[0][1] += wt * (float)v[1];
    acc[0][2] += wt * (float)v[2];
    acc[0][3] += wt * (float)v[3];
  }
  float4 b = *(const float4*)(bias + lane * 4);
  f16x4 r;
  r[0] = (f16)fmaxf(acc[0][0] + acc[1][0] + acc[2][0] + acc[3][0] + b.x, 0.f);
  r[1] = (f16)fmaxf(acc[0][1] + acc[1][1] + acc[2][1] + acc[3][1] + b.y, 0.f);
  r[2] = (f16)fmaxf(acc[0][2] + acc[1][2] + acc[2][2] + acc[3][2] + b.z, 0.f);
  r[3] = (f16)fmaxf(acc[0][3] + acc[1][3] + acc[2][3] + acc[3][3] + b.w, 0.f);
  *(f16x4*)(out + (size_t)wid * 256 + lane * 4) = r;
}

// ---------------- Aggregation D=64: one WAVE per row, quarter-wave edge slots ----

__global__ __launch_bounds__(256) void k_agg64(
    const f16* __restrict__ sup, const int* __restrict__ rowptr,
    const int2* __restrict__ ed, const float* __restrict__ bias,
    float* __restrict__ out, int n) {
  int wid = (blockIdx.x * THREADS + threadIdx.x) >> 6;
  int lane = threadIdx.x & 63;
  if (wid >= n) return;
  int p0 = rowptr[wid], p1 = rowptr[wid + 1];
  int q = lane >> 4;    // edge slot 0..3
  int hl = lane & 15;   // col group of 4

  const f16x4* supv = (const f16x4*)sup;
  float acc[2][4] = {};
  int p = p0;
  for (; p + 32 <= p1; p += 32) {
    int2 e[8];
#pragma unroll
    for (int j = 0; j < 8; ++j) e[j] = ed[p + 4 * j + q];
    f16x4 v[8];
#pragma unroll
    for (int j = 0; j < 8; ++j) v[j] = supv[(size_t)e[j].x * 16 + hl];
#pragma unroll
    for (int j = 0; j < 8; ++j) {
      float wt = __int_as_float(e[j].y);
      acc[j & 1][0] += wt * (float)v[j][0];
      acc[j & 1][1] += wt * (float)v[j][1];
      acc[j & 1][2] += wt * (float)v[j][2];
      acc[j & 1][3] += wt * (float)v[j][3];
    }
  }
  for (; p + 4 <= p1; p += 4) {
    int2 e0 = ed[p + q];
    float wt = __int_as_float(e0.y);
    f16x4 v = supv[(size_t)e0.x * 16 + hl];
    acc[0][0] += wt * (float)v[0];
    acc[0][1] += wt * (float)v[1];
    acc[0][2] += wt * (float)v[2];
    acc[0][3] += wt * (float)v[3];
  }
  if (p < p1) {
    int idx = p + q;
    int c = 0;
    float wt = 0.f;
    if (idx < p1) {
      int2 e0 = ed[idx];
      c = e0.x;
      wt = __int_as_float(e0.y);
    }
    f16x4 v = supv[(size_t)c * 16 + hl];
    acc[0][0] += wt * (float)v[0];
    acc[0][1] += wt * (float)v[1];
    acc[0][2] += wt * (float)v[2];
    acc[0][3] += wt * (float)v[3];
  }
  float t0 = acc[0][0] + acc[1][0];
  float t1 = acc[0][1] + acc[1][1];
  float t2 = acc[0][2] + acc[1][2];
  float t3 = acc[0][3] + acc[1][3];
  t0 += __shfl_xor(t0, 16); t0 += __shfl_xor(t0, 32);
  t1 += __shfl_xor(t1, 16); t1 += __shfl_xor(t1, 32);
  t2 += __shfl_xor(t2, 16); t2 += __shfl_xor(t2, 32);
  t3 += __shfl_xor(t3, 16); t3 += __shfl_xor(t3, 32);
  if (q == 0) {
    float4 b = *(const float4*)(bias + hl * 4);
    float4 res;
    res.x = fmaxf(t0 + b.x, 0.f);
    res.y = fmaxf(t1 + b.y, 0.f);
    res.z = fmaxf(t2 + b.z, 0.f);
    res.w = fmaxf(t3 + b.w, 0.f);
    *(float4*)(out + (size_t)wid * 64 + hl * 4) = res;
  }
}

// ---------------- BN stats ----------------

__global__ __launch_bounds__(256) void k_colstats(const f16* __restrict__ y,
                                                  float* __restrict__ sums, int n) {
  __shared__ float sh[8][256];
  int t = threadIdx.x;
  int cg = (t & 31) * 8;
  int rs = t >> 5;
  float s[8] = {}, s2[8] = {};
  for (int r = blockIdx.x * 8 + rs; r < n; r += gridDim.x * 8) {
    f16x8 v = *(const f16x8*)(y + (size_t)r * 256 + cg);
#pragma unroll
    for (int j = 0; j < 8; ++j) {
      float f = (float)v[j];
      s[j] += f;
      s2[j] += f * f;
    }
  }
#pragma unroll
  for (int j = 0; j < 8; ++j) sh[rs][cg + j] = s[j];
  __syncthreads();
  float tot = 0.f;
#pragma unroll
  for (int k = 0; k < 8; ++k) tot += sh[k][t];
  atomicAdd(&sums[t], tot);
  __syncthreads();
#pragma unroll
  for (int j = 0; j < 8; ++j) sh[rs][cg + j] = s2[j];
  __syncthreads();
  tot = 0.f;
#pragma unroll
  for (int k = 0; k < 8; ++k) tot += sh[k][t];
  atomicAdd(&sums[256 + t], tot);
}

// ---------------- launch ----------------

extern "C" void kernel_launch(void* const* d_in, const int* in_sizes, int n_in,
                              void* d_out, int out_size, void* d_ws, size_t ws_size,
                              hipStream_t stream) {
  const float* x = (const float*)d_in[0];
  const int* ei = (const int*)d_in[1];
  const float* ew = (const float*)d_in[2];
  const float* W1 = (const float*)d_in[3];
  const float* b1 = (const float*)d_in[4];
  const float* W2 = (const float*)d_in[5];
  const float* b2 = (const float*)d_in[6];
  const float* W3 = (const float*)d_in[7];
  const float* b3 = (const float*)d_in[8];
  float* out = (float*)d_out;

  const int N = in_sizes[0] / 512;  // 100000
  const int E = in_sizes[2];        // 3200000

  const int NB = (N + 127) >> BSH;            // 128-row buckets (782)
  const int NBLK = (E + EPB - 1) / EPB;       // binning blocks (391)
  const int scanN = NB * NBLK;
  const int ntiles = (scanN + 1023) / 1024;

  char* p = (char*)d_ws;
  auto alloc = [&](size_t bytes) {
    void* r = (void*)p;
    p += (bytes + 255) & ~(size_t)255;
    return r;
  };
  int* rowptr = (int*)alloc((size_t)(N + 1) * 4);
  int* cnt2d = (int*)alloc((size_t)scanN * 4);
  int* off2d = (int*)alloc((size_t)(scanN + 1) * 4);
  unsigned long long* tpub = (unsigned long long*)alloc((size_t)ntiles * 8);
  float* statZ = (float*)alloc(1536 * 4);
  float* sumsA = statZ;
  float* sumsB = statZ + 512;
  float* biasRowA = statZ + 1024;
  float* biasRowB = statZ + 1280;
  f16* Wt1 = (f16*)alloc((size_t)512 * 256 * 2);
  f16* Wt2 = (f16*)alloc((size_t)256 * 256 * 2);
  f16* Wt3 = (f16*)alloc((size_t)256 * 64 * 2);
  int2* temp = (int2*)alloc((size_t)E * 8);
  int2* ed = (int2*)alloc((size_t)E * 8);
  f16* sup = (f16*)alloc((size_t)N * 256 * 2);
  f16* act = (f16*)alloc((size_t)N * 256 * 2);

  const int* rows = ei;
  const int* colsIn = ei + E;

  const int gemmBlocks = (N + 127) / 128;
  const int aggBlocks = (N * 64 + THREADS - 1) / THREADS;
  const int convBlocks = (512 * 256 + 255) / 256;

  // --- front: hist + Wt1 convert + zero stats/scan-status (1 dispatch) ---
  k_hist_convW<<<NBLK + convBlocks, 256, 0, stream>>>(
      rows, cnt2d, E, NBLK, NB, W1, Wt1, 512, 256, statZ, tpub, ntiles);

  // --- single-pass scan ---
  k_scanDL<<<ntiles, 256, 0, stream>>>(cnt2d, off2d, tpub, scanN);

  // --- bin + layer-1 GEMM (1 dispatch, independent halves) ---
  k_bin_gemm<<<NBLK + gemmBlocks, 256, 0, stream>>>(
      rows, colsIn, ew, off2d, temp, E, NBLK, NB, x, Wt1, sup, N);

  // --- scatter into final CSR ---
  k_scatter<<<NB, 256, 0, stream>>>(temp, off2d, rowptr, ed, N, E, NBLK, NB);

  // --- Layer 1 aggregation ---
  k_agg256<<<aggBlocks, 256, 0, stream>>>(sup, rowptr, ed, b1, act, N);

  // --- BN1 + fold into W2 ---
  k_colstats<<<240, 256, 0, stream>>>(act, sumsA, N);
  k_bnfold<<<(256 * 256 + 255) / 256, 256, 0, stream>>>(W2, sumsA, Wt2, biasRowA, 256, 256, N);

  // --- Layer 2 ---
  k_gemm_mfma<256, true><<<gemmBlocks, 256, 0, stream>>>(act, Wt2, biasRowA, sup, N, 256);
  k_agg256<<<aggBlocks, 256, 0, stream>>>(sup, rowptr, ed, b2, act, N);

  // --- BN2 + fold into W3 ---
  k_colstats<<<240, 256, 0, stream>>>(act, sumsB, N);
  k_bnfold<<<(256 * 64 + 255) / 256, 256, 0, stream>>>(W3, sumsB, Wt3, biasRowB, 256, 64, N);

  // --- Layer 3 ---
  k_gemm_mfma<64, true><<<gemmBlocks, 256, 0, stream>>>(act, Wt3, biasRowB, sup, N, 256);
  k_agg64<<<aggBlocks, 256, 0, stream>>>(sup, rowptr, ed, b3, out, N);
}